// Round 4
// baseline (278.940 us; speedup 1.0000x reference)
//
#include <hip/hip_runtime.h>
#include <cmath>
#include <cfloat>

namespace {

constexpr int kB   = 1024;
constexpr int kL   = 64;
constexpr int kHid = 512;
constexpr int kLow = 20;
constexpr int kLM1 = 63;              // L-1
constexpr int kRowElems = kL * kLow;  // 1280 floats per batch row of h0/c0

__device__ __forceinline__ float sigf(float x) {
  return 1.0f / (1.0f + expf(-x));
}

// ---------------------------------------------------------------------------
// Phase 1: h0 = input_h @ W_reduce + b ; c0 = input_c @ W_reduce + b
// (73% of HBM floor; unchanged)
// ---------------------------------------------------------------------------
__global__ __launch_bounds__(256, 3)
void reduce_kernel(const float* __restrict__ Xh, const float* __restrict__ Xc,
                   const float* __restrict__ W, const float* __restrict__ bv,
                   float* __restrict__ H0, float* __restrict__ C0) {
  __shared__ float xs[64 * 132];   // 64 rows x 128 k (pitch 132 to break banks)
  __shared__ float wsm[128 * 20];  // W chunk

  const int bid = blockIdx.x;
  const float* __restrict__ X = (bid < kB) ? Xh : Xc;
  float* __restrict__ O       = (bid < kB) ? H0 : C0;
  const int b = bid & (kB - 1);
  X += (size_t)b * kL * kHid;
  O += (size_t)b * kRowElems;

  const int tid  = threadIdx.x;
  const int wave = tid >> 6;
  const int lane = tid & 63;

  float acc[20];
#pragma unroll
  for (int d = 0; d < 20; ++d) acc[d] = 0.0f;

  for (int ch = 0; ch < 4; ++ch) {
    __syncthreads();
#pragma unroll
    for (int r = 0; r < 8; ++r) {
      int f   = r * 256 + tid;          // float4 index within chunk
      int row = f >> 5;
      int c4  = (f & 31) << 2;
      float4 v = *(const float4*)(X + row * kHid + ch * 128 + c4);
      *(float4*)(xs + row * 132 + c4) = v;
    }
#pragma unroll
    for (int r = 0; r < 10; ++r) {
      int f = r * 256 + tid;
      wsm[f] = W[ch * 2560 + f];
    }
    __syncthreads();
#pragma unroll
    for (int kk = 0; kk < 32; ++kk) {
      int k = wave * 32 + kk;
      float x = xs[lane * 132 + k];
      const float4* wp = (const float4*)(wsm + k * 20);
      float4 w0 = wp[0], w1 = wp[1], w2 = wp[2], w3 = wp[3], w4 = wp[4];
      acc[0]  = fmaf(x, w0.x, acc[0]);  acc[1]  = fmaf(x, w0.y, acc[1]);
      acc[2]  = fmaf(x, w0.z, acc[2]);  acc[3]  = fmaf(x, w0.w, acc[3]);
      acc[4]  = fmaf(x, w1.x, acc[4]);  acc[5]  = fmaf(x, w1.y, acc[5]);
      acc[6]  = fmaf(x, w1.z, acc[6]);  acc[7]  = fmaf(x, w1.w, acc[7]);
      acc[8]  = fmaf(x, w2.x, acc[8]);  acc[9]  = fmaf(x, w2.y, acc[9]);
      acc[10] = fmaf(x, w2.z, acc[10]); acc[11] = fmaf(x, w2.w, acc[11]);
      acc[12] = fmaf(x, w3.x, acc[12]); acc[13] = fmaf(x, w3.y, acc[13]);
      acc[14] = fmaf(x, w3.z, acc[14]); acc[15] = fmaf(x, w3.w, acc[15]);
      acc[16] = fmaf(x, w4.x, acc[16]); acc[17] = fmaf(x, w4.y, acc[17]);
      acc[18] = fmaf(x, w4.z, acc[18]); acc[19] = fmaf(x, w4.w, acc[19]);
    }
  }

  __syncthreads();
  float* red = xs;  // reuse as scratch: 4*64*20 = 5120 floats
#pragma unroll
  for (int d = 0; d < 20; ++d) red[wave * 1280 + lane * 20 + d] = acc[d];
  __syncthreads();
#pragma unroll
  for (int r = 0; r < 5; ++r) {
    int f = r * 256 + tid;  // 1280 outputs, f = t*20 + d
    float s = (red[f] + red[1280 + f]) + (red[2560 + f] + red[3840 + f]);
    O[f] = s + bv[f % 20];
  }
}

// LDS-weight TreeLSTM eval of one (pair, dim) unit — used only for the init
// pass where all 63 pairs are evaluated in parallel across lanes.
#define EVAL_UNIT(A_, B2_, PS_, DD_, HN_)                                     \
  {                                                                           \
    float ai = bc[DD_], af = bc[20 + DD_], ag = bc[40 + DD_],                 \
          au = bc[60 + DD_], ao = bc[80 + DD_];                               \
    const int xa_ = (A_)*20, xb_ = (B2_)*20, wr_ = (DD_)*44;                  \
    _Pragma("unroll")                                                         \
    for (int kq = 0; kq < 10; ++kq) {                                         \
      const float4 xq = (kq < 5)                                              \
          ? *(const float4*)(h_state + xa_ + kq * 4)                          \
          : *(const float4*)(h_state + xb_ + (kq - 5) * 4);                   \
      const float4 wi = *(const float4*)(Wt + wr_ + kq * 4);                  \
      const float4 wf = *(const float4*)(Wt + 880  + wr_ + kq * 4);           \
      const float4 wg = *(const float4*)(Wt + 1760 + wr_ + kq * 4);           \
      const float4 wu = *(const float4*)(Wt + 2640 + wr_ + kq * 4);           \
      const float4 wo = *(const float4*)(Wt + 3520 + wr_ + kq * 4);           \
      ai = fmaf(xq.x, wi.x, ai); ai = fmaf(xq.y, wi.y, ai);                   \
      ai = fmaf(xq.z, wi.z, ai); ai = fmaf(xq.w, wi.w, ai);                   \
      af = fmaf(xq.x, wf.x, af); af = fmaf(xq.y, wf.y, af);                   \
      af = fmaf(xq.z, wf.z, af); af = fmaf(xq.w, wf.w, af);                   \
      ag = fmaf(xq.x, wg.x, ag); ag = fmaf(xq.y, wg.y, ag);                   \
      ag = fmaf(xq.z, wg.z, ag); ag = fmaf(xq.w, wg.w, ag);                   \
      au = fmaf(xq.x, wu.x, au); au = fmaf(xq.y, wu.y, au);                   \
      au = fmaf(xq.z, wu.z, au); au = fmaf(xq.w, wu.w, au);                   \
      ao = fmaf(xq.x, wo.x, ao); ao = fmaf(xq.y, wo.y, ao);                   \
      ao = fmaf(xq.z, wo.z, ao); ao = fmaf(xq.w, wo.w, ao);                   \
    }                                                                         \
    const float cl_ = c_state[(A_)*20 + (DD_)],                               \
                cr_ = c_state[(B2_)*20 + (DD_)];                              \
    const float cn_ = cl_ * sigf(af + 1.0f) + cr_ * sigf(ag + 1.0f) +         \
                      tanhf(au) * sigf(ai);                                   \
    (HN_) = sigf(ao) * tanhf(cn_);                                            \
    nh[(PS_)*20 + (DD_)] = (HN_);                                             \
    nc[(PS_)*20 + (DD_)] = cn_;                                               \
  }

// Register-weight TreeLSTM eval (main loop): lane = (half = lane>>5 picks the
// K-half / child, dd = lane&31 the output dim). Weights live in wi/wfl/wfr/
// wu/wo (registers). Evaluates pair (A_,B2_) into slot PS_, logit -> lgt[NEWPOS_].
#define EVAL_REG(A_, B2_, PS_, NEWPOS_)                                       \
  {                                                                           \
    const int srcrow_ = (half ? (B2_) : (A_)) * 20;                           \
    float xr_[20];                                                            \
    _Pragma("unroll")                                                         \
    for (int q_ = 0; q_ < 5; ++q_) {                                          \
      const float4 t_ = *(const float4*)(h_state + srcrow_ + q_ * 4);         \
      xr_[q_ * 4 + 0] = t_.x; xr_[q_ * 4 + 1] = t_.y;                         \
      xr_[q_ * 4 + 2] = t_.z; xr_[q_ * 4 + 3] = t_.w;                         \
    }                                                                         \
    float si_ = 0.f, sfl_ = 0.f, sfr_ = 0.f, su_ = 0.f, so_ = 0.f;            \
    _Pragma("unroll")                                                         \
    for (int kk_ = 0; kk_ < 20; ++kk_) {                                      \
      si_  = fmaf(xr_[kk_], wi[kk_],  si_);                                   \
      sfl_ = fmaf(xr_[kk_], wfl[kk_], sfl_);                                  \
      sfr_ = fmaf(xr_[kk_], wfr[kk_], sfr_);                                  \
      su_  = fmaf(xr_[kk_], wu[kk_],  su_);                                   \
      so_  = fmaf(xr_[kk_], wo[kk_],  so_);                                   \
    }                                                                         \
    si_  += __shfl_xor(si_, 32);                                              \
    sfl_ += __shfl_xor(sfl_, 32);                                             \
    sfr_ += __shfl_xor(sfr_, 32);                                             \
    su_  += __shfl_xor(su_, 32);                                              \
    so_  += __shfl_xor(so_, 32);                                              \
    si_ += bi; sfl_ += bfl; sfr_ += bfr; su_ += bu; so_ += bo;                \
    const float cl_ = c_state[(A_)*20 + ddc];                                 \
    const float cr_ = c_state[(B2_)*20 + ddc];                                \
    const float cn_ = cl_ * sigf(sfl_ + 1.0f) + cr_ * sigf(sfr_ + 1.0f) +     \
                      tanhf(su_) * sigf(si_);                                 \
    const float hn_ = sigf(so_) * tanhf(cn_);                                 \
    if (lane < 20) { nh[(PS_)*20 + ddc] = hn_; nc[(PS_)*20 + ddc] = cn_; }    \
    float part_ = (lane < 20) ? hn_ * qq : 0.0f;                              \
    _Pragma("unroll")                                                         \
    for (int off_ = 32; off_ > 0; off_ >>= 1)                                 \
      part_ += __shfl_xor(part_, off_);                                       \
    if (lane == 0) lgt[NEWPOS_] = part_;                                      \
  }

// ---------------------------------------------------------------------------
// Phase 2: per-row Gumbel tree pyramid, ONE WAVE per row, weights in VGPRs.
// ---------------------------------------------------------------------------
__global__ __launch_bounds__(64, 1)
void pyramid_kernel(const float* __restrict__ H0, const float* __restrict__ C0,
                    const float* __restrict__ Wc, const float* __restrict__ bcg,
                    const float* __restrict__ query, const float* __restrict__ U,
                    const int* __restrict__ length, float* __restrict__ out) {
  __shared__ float h_state[64 * 20];
  __shared__ float c_state[64 * 20];
  __shared__ float nh[63 * 20];     // cached pair h_new, indexed by pair SLOT
  __shared__ float nc[63 * 20];     // cached pair c_new
  __shared__ float Wt[100 * 44];    // transposed W_comp: Wt[c][k], pitch 44
  __shared__ float bc[100];
  __shared__ float qv[20];
  __shared__ float lgt[64];         // logits, POSITION-indexed (shifted)
  __shared__ int   idxs[64];        // logical position -> h/c slot
  __shared__ int   pidx[64];        // logical pair -> nh/nc slot

  const int b    = blockIdx.x;
  const int lane = threadIdx.x;     // one wave: lane == tid
  const int half = lane >> 5;       // K-half: 0 -> left child, 1 -> right child
  const int dd   = lane & 31;       // output dim (active when < 20)
  const int ddc  = dd < 20 ? dd : 0;
  int len = length[b];
  len = len < 1 ? 1 : (len > 64 ? 64 : len);

  // ---- stage (single wave; in-order DS pipeline orders everything) ----
  {
    const float4* h4 = (const float4*)(H0 + (size_t)b * kRowElems);
    const float4* c4 = (const float4*)(C0 + (size_t)b * kRowElems);
#pragma unroll
    for (int r = 0; r < 5; ++r) {
      int f = r * 64 + lane;  // 320 float4 per array
      ((float4*)h_state)[f] = h4[f];
      ((float4*)c_state)[f] = c4[f];
    }
  }
  for (int f = lane; f < 4000; f += 64) {
    int c = f / 40, k = f - c * 40;
    Wt[c * 44 + k] = Wc[k * 100 + c];
  }
  for (int f = lane; f < 100; f += 64) bc[f] = bcg[f];
  if (lane < 20) qv[lane] = query[lane];
  idxs[lane] = lane;
  pidx[lane] = lane;
  lgt[lane] = -FLT_MAX;

  const int col = lane < 62 ? lane : 62;  // U row has 63 entries
  float u0 = U[b * kLM1 + col];           // row 0, consumed at i=0

  // ---- init: evaluate all 63 adjacent pairs (LDS weights, parallel) ----
#pragma unroll 1
  for (int r = 0; r < 20; ++r) {
    int uu = r * 64 + lane;
    if (uu < 1260) {
      int p = uu / 20, d2 = uu - p * 20;
      float hn_;
      EVAL_UNIT(p, p + 1, p, d2, hn_);
      (void)hn_;
    }
  }
  if (lane < 63) {
    float s = 0.0f;
#pragma unroll
    for (int d = 0; d < 20; ++d) s = fmaf(nh[lane * 20 + d], qv[d], s);
    lgt[lane] = s;
  }

  // ---- load this lane's gate-weight columns into registers (100 VGPRs) ----
  float wi[20], wfl[20], wfr[20], wu[20], wo[20];
#pragma unroll
  for (int q = 0; q < 5; ++q) {
    float4 t;
    t = *(const float4*)(Wt + (0  + ddc) * 44 + half * 20 + q * 4);
    wi[q*4+0]=t.x;  wi[q*4+1]=t.y;  wi[q*4+2]=t.z;  wi[q*4+3]=t.w;
    t = *(const float4*)(Wt + (20 + ddc) * 44 + half * 20 + q * 4);
    wfl[q*4+0]=t.x; wfl[q*4+1]=t.y; wfl[q*4+2]=t.z; wfl[q*4+3]=t.w;
    t = *(const float4*)(Wt + (40 + ddc) * 44 + half * 20 + q * 4);
    wfr[q*4+0]=t.x; wfr[q*4+1]=t.y; wfr[q*4+2]=t.z; wfr[q*4+3]=t.w;
    t = *(const float4*)(Wt + (60 + ddc) * 44 + half * 20 + q * 4);
    wu[q*4+0]=t.x;  wu[q*4+1]=t.y;  wu[q*4+2]=t.z;  wu[q*4+3]=t.w;
    t = *(const float4*)(Wt + (80 + ddc) * 44 + half * 20 + q * 4);
    wo[q*4+0]=t.x;  wo[q*4+1]=t.y;  wo[q*4+2]=t.z;  wo[q*4+3]=t.w;
  }
  const float bi  = bc[ddc],      bfl = bc[20 + ddc], bfr = bc[40 + ddc],
              bu  = bc[60 + ddc], bo  = bc[80 + ddc];
  const float qq  = qv[ddc];

  float gcur = -logf(-logf(u0 + 1e-20f) + 1e-20f);

  const int nIter = len - 1;
#pragma unroll 1
  for (int i = 0; i < nIter; ++i) {
    const int n = kL - i;  // current sequence length

    // ---- z = logit + gumbel; argmax (ties -> lowest index) ----
    float zz = -FLT_MAX;
    int   ji = lane;
    if ((lane <= n - 2) && ((i + 1 + lane) < len)) zz = lgt[lane] + gcur;
#pragma unroll
    for (int off = 32; off > 0; off >>= 1) {
      float oz = __shfl_xor(zz, off);
      int   oi = __shfl_xor(ji, off);
      if (oz > zz || (oz == zz && oi < ji)) { zz = oz; ji = oi; }
    }
    const int k = ji;  // wave-uniform

    // ---- prefetch next gumbel row; transform off the critical path ----
    float gnext = 0.0f;
    if (i + 1 < kLM1) {
      const float un = U[(i + 1) * (kB * kLM1) + b * kLM1 + col];
      gnext = -logf(-logf(un + 1e-20f) + 1e-20f);
    }

    // ---- pre-shift reads: everything eval will need ----
    const int tgt = idxs[k];
    const int psk = pidx[k];
    int iA = 0, pA = 0, iB = 0;
    if (k >= 1)     { iA = idxs[k - 1]; pA = pidx[k - 1]; }
    if (k <= n - 3) { iB = idxs[k + 2]; }

    // ---- merge value + shift-source reads ----
    float nhv = 0.0f, ncv = 0.0f;
    if (lane < 20) { nhv = nh[psk * 20 + lane]; ncv = nc[psk * 20 + lane]; }
    const bool doI = (lane >= k + 1) && (lane <= n - 2);
    const bool doP = (lane >= k + 1) && (lane <= n - 3);
    const int  ln1 = lane < 63 ? lane + 1 : 63;
    int   vI = doI ? idxs[ln1] : 0;
    int   vP = doP ? pidx[ln1] : 0;
    float vL = doP ? lgt[ln1]  : 0.0f;
    __builtin_amdgcn_wave_barrier();  // reads above scheduled before writes below
    if (lane < 20) {
      h_state[tgt * 20 + lane] = nhv;
      c_state[tgt * 20 + lane] = ncv;
    }
    if (doI) idxs[lane] = vI;
    if (doP) { pidx[lane] = vP; lgt[lane] = vL; }

    // ---- evaluate the (<=2) invalidated pairs with register weights ----
    if (i < len - 2) {
      if (k >= 1)     EVAL_REG(iA, tgt, pA, k - 1);
      if (k <= n - 3) EVAL_REG(tgt, iB, psk, k);
    }

    gcur = gnext;
  }

  if (lane < 20) {
    out[b * 20 + lane] = h_state[idxs[0] * 20 + lane];
  }
}

}  // namespace

extern "C" void kernel_launch(void* const* d_in, const int* in_sizes, int n_in,
                              void* d_out, int out_size, void* d_ws, size_t ws_size,
                              hipStream_t stream) {
  const float* input_h  = (const float*)d_in[0];
  const float* input_c  = (const float*)d_in[1];
  const float* W_reduce = (const float*)d_in[2];
  const float* b_reduce = (const float*)d_in[3];
  const float* W_comp   = (const float*)d_in[4];
  const float* b_comp   = (const float*)d_in[5];
  const float* query    = (const float*)d_in[6];
  const float* u_noise  = (const float*)d_in[7];
  const int*   length   = (const int*)d_in[8];
  float* out = (float*)d_out;

  float* H0 = (float*)d_ws;
  float* C0 = H0 + (size_t)kB * kL * kLow;

  reduce_kernel<<<dim3(2 * kB), dim3(256), 0, stream>>>(
      input_h, input_c, W_reduce, b_reduce, H0, C0);
  pyramid_kernel<<<dim3(kB), dim3(64), 0, stream>>>(
      H0, C0, W_comp, b_comp, query, u_noise, length, out);
}

// Round 5
// 214.153 us; speedup vs baseline: 1.3025x; 1.3025x over previous
//
#include <hip/hip_runtime.h>
#include <cmath>
#include <cfloat>

namespace {

constexpr int kB   = 1024;
constexpr int kL   = 64;
constexpr int kHid = 512;
constexpr int kLow = 20;
constexpr int kLM1 = 63;              // L-1
constexpr int kRowElems = kL * kLow;  // 1280 floats per batch row of h0/c0

__device__ __forceinline__ float fsig(float x) {
  // 1/(1+e^-x); rcp approx (~1ulp) fine at this tolerance. x=+inf/-inf -> 1/0 ok.
  return __builtin_amdgcn_rcpf(1.0f + __expf(-x));
}
__device__ __forceinline__ float ftanhf(float x) {
  // 1 - 2/(1+e^{2x}); large |x| saturates correctly via exp->{0,inf}.
  return 1.0f - 2.0f * __builtin_amdgcn_rcpf(1.0f + __expf(2.0f * x));
}
__device__ __forceinline__ int rdl_i(int v, int l) {
  return __builtin_amdgcn_readlane(v, l);
}
__device__ __forceinline__ float rdl_f(float v, int l) {
  return __int_as_float(__builtin_amdgcn_readlane(__float_as_int(v), l));
}

// ---------------------------------------------------------------------------
// Phase 1: h0 = input_h @ W_reduce + b ; c0 = input_c @ W_reduce + b
// (~73% of HBM floor; unchanged from R3)
// ---------------------------------------------------------------------------
__global__ __launch_bounds__(256, 3)
void reduce_kernel(const float* __restrict__ Xh, const float* __restrict__ Xc,
                   const float* __restrict__ W, const float* __restrict__ bv,
                   float* __restrict__ H0, float* __restrict__ C0) {
  __shared__ float xs[64 * 132];   // 64 rows x 128 k (pitch 132 to break banks)
  __shared__ float wsm[128 * 20];  // W chunk

  const int bid = blockIdx.x;
  const float* __restrict__ X = (bid < kB) ? Xh : Xc;
  float* __restrict__ O       = (bid < kB) ? H0 : C0;
  const int b = bid & (kB - 1);
  X += (size_t)b * kL * kHid;
  O += (size_t)b * kRowElems;

  const int tid  = threadIdx.x;
  const int wave = tid >> 6;
  const int lane = tid & 63;

  float acc[20];
#pragma unroll
  for (int d = 0; d < 20; ++d) acc[d] = 0.0f;

  for (int ch = 0; ch < 4; ++ch) {
    __syncthreads();
#pragma unroll
    for (int r = 0; r < 8; ++r) {
      int f   = r * 256 + tid;          // float4 index within chunk
      int row = f >> 5;
      int c4  = (f & 31) << 2;
      float4 v = *(const float4*)(X + row * kHid + ch * 128 + c4);
      *(float4*)(xs + row * 132 + c4) = v;
    }
#pragma unroll
    for (int r = 0; r < 10; ++r) {
      int f = r * 256 + tid;
      wsm[f] = W[ch * 2560 + f];
    }
    __syncthreads();
#pragma unroll
    for (int kk = 0; kk < 32; ++kk) {
      int k = wave * 32 + kk;
      float x = xs[lane * 132 + k];
      const float4* wp = (const float4*)(wsm + k * 20);
      float4 w0 = wp[0], w1 = wp[1], w2 = wp[2], w3 = wp[3], w4 = wp[4];
      acc[0]  = fmaf(x, w0.x, acc[0]);  acc[1]  = fmaf(x, w0.y, acc[1]);
      acc[2]  = fmaf(x, w0.z, acc[2]);  acc[3]  = fmaf(x, w0.w, acc[3]);
      acc[4]  = fmaf(x, w1.x, acc[4]);  acc[5]  = fmaf(x, w1.y, acc[5]);
      acc[6]  = fmaf(x, w1.z, acc[6]);  acc[7]  = fmaf(x, w1.w, acc[7]);
      acc[8]  = fmaf(x, w2.x, acc[8]);  acc[9]  = fmaf(x, w2.y, acc[9]);
      acc[10] = fmaf(x, w2.z, acc[10]); acc[11] = fmaf(x, w2.w, acc[11]);
      acc[12] = fmaf(x, w3.x, acc[12]); acc[13] = fmaf(x, w3.y, acc[13]);
      acc[14] = fmaf(x, w3.z, acc[14]); acc[15] = fmaf(x, w3.w, acc[15]);
      acc[16] = fmaf(x, w4.x, acc[16]); acc[17] = fmaf(x, w4.y, acc[17]);
      acc[18] = fmaf(x, w4.z, acc[18]); acc[19] = fmaf(x, w4.w, acc[19]);
    }
  }

  __syncthreads();
  float* red = xs;  // reuse as scratch: 4*64*20 = 5120 floats
#pragma unroll
  for (int d = 0; d < 20; ++d) red[wave * 1280 + lane * 20 + d] = acc[d];
  __syncthreads();
#pragma unroll
  for (int r = 0; r < 5; ++r) {
    int f = r * 256 + tid;  // 1280 outputs, f = t*20 + d
    float s = (red[f] + red[1280 + f]) + (red[2560 + f] + red[3840 + f]);
    O[f] = s + bv[f % 20];
  }
}

// LDS-weight TreeLSTM eval of one (pair, dim) unit — used only for the init
// pass where all 63 pairs are evaluated in parallel across lanes.
#define EVAL_UNIT(A_, B2_, PS_, DD_, HN_)                                     \
  {                                                                           \
    float ai = bcs[DD_], af = bcs[20 + DD_], ag = bcs[40 + DD_],              \
          au = bcs[60 + DD_], ao = bcs[80 + DD_];                             \
    const int xa_ = (A_)*20, xb_ = (B2_)*20, wr_ = (DD_)*44;                  \
    _Pragma("unroll")                                                         \
    for (int kq = 0; kq < 10; ++kq) {                                         \
      const float4 xq = (kq < 5)                                              \
          ? *(const float4*)(h_state + xa_ + kq * 4)                          \
          : *(const float4*)(h_state + xb_ + (kq - 5) * 4);                   \
      const float4 wi = *(const float4*)(Wt + wr_ + kq * 4);                  \
      const float4 wf = *(const float4*)(Wt + 880  + wr_ + kq * 4);           \
      const float4 wg = *(const float4*)(Wt + 1760 + wr_ + kq * 4);           \
      const float4 wu = *(const float4*)(Wt + 2640 + wr_ + kq * 4);           \
      const float4 wo = *(const float4*)(Wt + 3520 + wr_ + kq * 4);           \
      ai = fmaf(xq.x, wi.x, ai); ai = fmaf(xq.y, wi.y, ai);                   \
      ai = fmaf(xq.z, wi.z, ai); ai = fmaf(xq.w, wi.w, ai);                   \
      af = fmaf(xq.x, wf.x, af); af = fmaf(xq.y, wf.y, af);                   \
      af = fmaf(xq.z, wf.z, af); af = fmaf(xq.w, wf.w, af);                   \
      ag = fmaf(xq.x, wg.x, ag); ag = fmaf(xq.y, wg.y, ag);                   \
      ag = fmaf(xq.z, wg.z, ag); ag = fmaf(xq.w, wg.w, ag);                   \
      au = fmaf(xq.x, wu.x, au); au = fmaf(xq.y, wu.y, au);                   \
      au = fmaf(xq.z, wu.z, au); au = fmaf(xq.w, wu.w, au);                   \
      ao = fmaf(xq.x, wo.x, ao); ao = fmaf(xq.y, wo.y, ao);                   \
      ao = fmaf(xq.z, wo.z, ao); ao = fmaf(xq.w, wo.w, ao);                   \
    }                                                                         \
    const float cl_ = c_state[(A_)*20 + (DD_)],                               \
                cr_ = c_state[(B2_)*20 + (DD_)];                              \
    const float cn_ = cl_ * fsig(af + 1.0f) + cr_ * fsig(ag + 1.0f) +         \
                      ftanhf(au) * fsig(ai);                                  \
    (HN_) = fsig(ao) * ftanhf(cn_);                                           \
    nh[(PS_)*20 + (DD_)] = (HN_);                                             \
    nc[(PS_)*20 + (DD_)] = cn_;                                               \
  }

// Register-weight eval for the main loop (R3's parallel-2-pair layout kept):
// weights w0..w4[40] pinned in VGPRs; only x (10xb128) + c (2xb32) from LDS.
#define EVAL_REGW(A_, B2_, PS_)                                               \
  {                                                                           \
    float xr[40];                                                             \
    _Pragma("unroll")                                                         \
    for (int q = 0; q < 5; ++q) {                                             \
      const float4 t = *(const float4*)(h_state + (A_)*20 + q * 4);           \
      xr[q*4+0]=t.x; xr[q*4+1]=t.y; xr[q*4+2]=t.z; xr[q*4+3]=t.w;             \
    }                                                                         \
    _Pragma("unroll")                                                         \
    for (int q = 0; q < 5; ++q) {                                             \
      const float4 t = *(const float4*)(h_state + (B2_)*20 + q * 4);          \
      xr[20+q*4+0]=t.x; xr[20+q*4+1]=t.y; xr[20+q*4+2]=t.z; xr[20+q*4+3]=t.w; \
    }                                                                         \
    float si = bi, sfl = bfl, sfr = bfr, su = bu, so = bo;                    \
    _Pragma("unroll")                                                         \
    for (int kk = 0; kk < 40; ++kk) {                                         \
      si  = fmaf(xr[kk], w0[kk], si);                                         \
      sfl = fmaf(xr[kk], w1[kk], sfl);                                        \
      sfr = fmaf(xr[kk], w2[kk], sfr);                                        \
      su  = fmaf(xr[kk], w3[kk], su);                                         \
      so  = fmaf(xr[kk], w4[kk], so);                                         \
    }                                                                         \
    const float cl_ = c_state[(A_)*20 + dd];                                  \
    const float cr_ = c_state[(B2_)*20 + dd];                                 \
    const float cn_ = cl_ * fsig(sfl + 1.0f) + cr_ * fsig(sfr + 1.0f) +       \
                      ftanhf(su) * fsig(si);                                  \
    const float hn_ = fsig(so) * ftanhf(cn_);                                 \
    nh[(PS_)*20 + dd] = hn_;                                                  \
    nc[(PS_)*20 + dd] = cn_;                                                  \
    part_ = hn_ * qq;                                                         \
  }

// ---------------------------------------------------------------------------
// Phase 2: per-row Gumbel tree pyramid, ONE WAVE per row.
// Weights pinned in VGPRs (asm), idxs/pidx/lgt in registers (1 entry/lane).
// LDS 38.4 KB -> 4 blocks/CU.
// ---------------------------------------------------------------------------
__global__ __launch_bounds__(64, 1)
void pyramid_kernel(const float* __restrict__ H0, const float* __restrict__ C0,
                    const float* __restrict__ Wc, const float* __restrict__ bcg,
                    const float* __restrict__ query, const float* __restrict__ U,
                    const int* __restrict__ length, float* __restrict__ out) {
  __shared__ float h_state[64 * 20];
  __shared__ float c_state[64 * 20];
  __shared__ float nh[63 * 20];     // cached pair h_new, indexed by pair SLOT
  __shared__ float nc[63 * 20];     // cached pair c_new
  __shared__ float Wt[100 * 44];    // transposed W_comp: Wt[c][k], pitch 44
  __shared__ float bcs[100];
  __shared__ float qvs[20];

  const int b    = blockIdx.x;
  const int lane = threadIdx.x;     // one wave: lane == tid
  const int dd   = lane & 31;       // output dim within eval group
  const int ddc  = dd < 20 ? dd : 19;
  int len = length[b];
  len = len < 1 ? 1 : (len > 64 ? 64 : len);

  // ---- stage ----
  {
    const float4* h4 = (const float4*)(H0 + (size_t)b * kRowElems);
    const float4* c4 = (const float4*)(C0 + (size_t)b * kRowElems);
#pragma unroll
    for (int r = 0; r < 5; ++r) {
      int f = r * 64 + lane;  // 320 float4 per array
      ((float4*)h_state)[f] = h4[f];
      ((float4*)c_state)[f] = c4[f];
    }
  }
  for (int f = lane; f < 4000; f += 64) {
    int c = f / 40, k = f - c * 40;
    Wt[c * 44 + k] = Wc[k * 100 + c];
  }
  for (int f = lane; f < 100; f += 64) bcs[f] = bcg[f];
  if (lane < 20) qvs[lane] = query[lane];

  // per-lane register copies of position-indexed bookkeeping
  int   idx_r  = lane;   // position lane -> h/c slot
  int   pidx_r = lane;   // position lane -> nh/nc slot
  float lgt_r  = -FLT_MAX;

  const int col = lane < 62 ? lane : 62;  // U row has 63 entries
  float u0 = U[b * kLM1 + col];           // row 0, consumed at i=0

  // ---- init: evaluate all 63 adjacent pairs (LDS weights, parallel) ----
#pragma unroll 1
  for (int r = 0; r < 20; ++r) {
    int uu = r * 64 + lane;
    if (uu < 1260) {
      int p = uu / 20, d2 = uu - p * 20;
      float hn_;
      EVAL_UNIT(p, p + 1, p, d2, hn_);
      (void)hn_;
    }
  }
  if (lane < 63) {
    float s = 0.0f;
#pragma unroll
    for (int q = 0; q < 5; ++q) {
      const float4 t  = *(const float4*)(nh  + lane * 20 + q * 4);
      const float4 qv = *(const float4*)(qvs + q * 4);
      s = fmaf(t.x, qv.x, s); s = fmaf(t.y, qv.y, s);
      s = fmaf(t.z, qv.z, s); s = fmaf(t.w, qv.w, s);
    }
    lgt_r = s;
  }

  // ---- load this lane's full gate-weight columns into registers (200) ----
  float w0[40], w1[40], w2[40], w3[40], w4[40];
#pragma unroll
  for (int q = 0; q < 10; ++q) {
    float4 t;
    t = *(const float4*)(Wt + (0  + ddc) * 44 + q * 4);
    w0[q*4+0]=t.x; w0[q*4+1]=t.y; w0[q*4+2]=t.z; w0[q*4+3]=t.w;
    t = *(const float4*)(Wt + (20 + ddc) * 44 + q * 4);
    w1[q*4+0]=t.x; w1[q*4+1]=t.y; w1[q*4+2]=t.z; w1[q*4+3]=t.w;
    t = *(const float4*)(Wt + (40 + ddc) * 44 + q * 4);
    w2[q*4+0]=t.x; w2[q*4+1]=t.y; w2[q*4+2]=t.z; w2[q*4+3]=t.w;
    t = *(const float4*)(Wt + (60 + ddc) * 44 + q * 4);
    w3[q*4+0]=t.x; w3[q*4+1]=t.y; w3[q*4+2]=t.z; w3[q*4+3]=t.w;
    t = *(const float4*)(Wt + (80 + ddc) * 44 + q * 4);
    w4[q*4+0]=t.x; w4[q*4+1]=t.y; w4[q*4+2]=t.z; w4[q*4+3]=t.w;
  }
  // Opaque pin: after this, remat-from-LDS is illegal; values must stay in
  // VGPRs (budget 512 at 1 wave/SIMD). Verify via VGPR_Count >= ~280.
#pragma unroll
  for (int j = 0; j < 40; ++j) {
    asm volatile("" : "+v"(w0[j]), "+v"(w1[j]), "+v"(w2[j]),
                      "+v"(w3[j]), "+v"(w4[j]));
  }
  const float bi  = bcs[ddc],      bfl = bcs[20 + ddc], bfr = bcs[40 + ddc],
              bu  = bcs[60 + ddc], bo  = bcs[80 + ddc];
  const float qq  = qvs[ddc];

  float gcur = -__logf(-__logf(u0 + 1e-20f) + 1e-20f);

  const int nIter = len - 1;
#pragma unroll 1
  for (int i = 0; i < nIter; ++i) {
    const int n = kL - i;  // current sequence length

    // ---- z = logit + gumbel; argmax (ties -> lowest index) ----
    float zz = -FLT_MAX;
    int   ji = lane;
    if ((lane <= n - 2) && ((i + 1 + lane) < len)) zz = lgt_r + gcur;
#pragma unroll
    for (int off = 32; off > 0; off >>= 1) {
      float oz = __shfl_xor(zz, off);
      int   oi = __shfl_xor(ji, off);
      if (oz > zz || (oz == zz && oi < ji)) { zz = oz; ji = oi; }
    }
    const int k = ji;  // wave-uniform

    // ---- prefetch next gumbel row; transform off the critical path ----
    float gnext = 0.0f;
    if (i + 1 < kLM1) {
      const float un = U[(i + 1) * (kB * kLM1) + b * kLM1 + col];
      gnext = -__logf(-__logf(un + 1e-20f) + 1e-20f);
    }

    // ---- pre-shift lookups via readlane (VALU, no LDS) ----
    const int km1 = (k >= 1) ? k - 1 : 0;
    const int kp2 = (k <= n - 3) ? k + 2 : 0;
    const int tgt = rdl_i(idx_r,  k);
    const int psk = rdl_i(pidx_r, k);
    const int iA  = rdl_i(idx_r,  km1);
    const int pA  = rdl_i(pidx_r, km1);
    const int iB  = rdl_i(idx_r,  kp2);

    // ---- merge: winner pair's cached (h,c) -> state slot tgt ----
    if (lane < 20) {
      const float nhv = nh[psk * 20 + lane];
      const float ncv = nc[psk * 20 + lane];
      h_state[tgt * 20 + lane] = nhv;
      c_state[tgt * 20 + lane] = ncv;
    }

    // ---- shift position-indexed registers (collapse position k+1..) ----
    {
      const int  ln1 = lane < 63 ? lane + 1 : 63;
      const int   sI = __shfl(idx_r,  ln1);
      const int   sP = __shfl(pidx_r, ln1);
      const float sL = __shfl(lgt_r,  ln1);
      const bool doI = (lane >= k + 1) && (lane <= n - 2);
      const bool doP = (lane >= k + 1) && (lane <= n - 3);
      if (doI) idx_r = sI;
      if (doP) { pidx_r = sP; lgt_r = sL; }
    }

    // ---- evaluate the (<=2) invalidated pairs (register weights) ----
    if (i < len - 2) {
      const int  p    = lane >> 5;
      const bool hasB = (k >= 1) && (k <= n - 3);
      int A_, B2_, PS_;
      if (p == 0) {
        A_  = (k >= 1) ? iA  : tgt;
        B2_ = (k >= 1) ? tgt : iB;
        PS_ = (k >= 1) ? pA  : psk;
      } else {
        A_ = tgt; B2_ = iB; PS_ = psk;
      }
      const bool act = (dd < 20) && (p == 0 || hasB);
      float part_ = 0.0f;
      if (act) { EVAL_REGW(A_, B2_, PS_); }
#pragma unroll
      for (int off = 16; off > 0; off >>= 1) part_ += __shfl_xor(part_, off);
      const int   pos0 = (k >= 1) ? k - 1 : k;
      const float vA   = rdl_f(part_, 0);
      const float vB   = rdl_f(part_, 32);
      if (lane == pos0) lgt_r = vA;
      if (hasB && lane == k) lgt_r = vB;
    }

    gcur = gnext;
  }

  const int root = rdl_i(idx_r, 0);
  if (lane < 20) {
    out[b * 20 + lane] = h_state[root * 20 + lane];
  }
}

}  // namespace

extern "C" void kernel_launch(void* const* d_in, const int* in_sizes, int n_in,
                              void* d_out, int out_size, void* d_ws, size_t ws_size,
                              hipStream_t stream) {
  const float* input_h  = (const float*)d_in[0];
  const float* input_c  = (const float*)d_in[1];
  const float* W_reduce = (const float*)d_in[2];
  const float* b_reduce = (const float*)d_in[3];
  const float* W_comp   = (const float*)d_in[4];
  const float* b_comp   = (const float*)d_in[5];
  const float* query    = (const float*)d_in[6];
  const float* u_noise  = (const float*)d_in[7];
  const int*   length   = (const int*)d_in[8];
  float* out = (float*)d_out;

  float* H0 = (float*)d_ws;
  float* C0 = H0 + (size_t)kB * kL * kLow;

  reduce_kernel<<<dim3(2 * kB), dim3(256), 0, stream>>>(
      input_h, input_c, W_reduce, b_reduce, H0, C0);
  pyramid_kernel<<<dim3(kB), dim3(64), 0, stream>>>(
      H0, C0, W_comp, b_comp, query, u_noise, length, out);
}

// Round 6
// 174.656 us; speedup vs baseline: 1.5971x; 1.2261x over previous
//
#include <hip/hip_runtime.h>
#include <cmath>
#include <cfloat>

namespace {

constexpr int kB   = 1024;
constexpr int kL   = 64;
constexpr int kHid = 512;
constexpr int kLow = 20;
constexpr int kLM1 = 63;              // L-1
constexpr int kRowElems = kL * kLow;  // 1280 floats per batch row of h0/c0

__device__ __forceinline__ float fsig(float x) {
  return __builtin_amdgcn_rcpf(1.0f + __expf(-x));
}
__device__ __forceinline__ float ftanhf(float x) {
  return 1.0f - 2.0f * __builtin_amdgcn_rcpf(1.0f + __expf(2.0f * x));
}
__device__ __forceinline__ int rdl_i(int v, int l) {
  return __builtin_amdgcn_readlane(v, l);
}
__device__ __forceinline__ float rdl_f(float v, int l) {
  return __int_as_float(__builtin_amdgcn_readlane(__float_as_int(v), l));
}

// DPP helpers (ctrl must be a literal -> macros).
// 0xB1 = quad_perm[1,0,3,2] (xor1)   0x4E = quad_perm[2,3,0,1] (xor2)
// 0x141 = row_half_mirror            0x140 = row_mirror
// 0x142 = row_bcast15                0x143 = row_bcast31
// 0x101 = row_shl:1  (lane i <- lane i+1 within each 16-lane row)
#define DPPI(v, ctrl) __builtin_amdgcn_update_dpp((v), (v), (ctrl), 0xF, 0xF, false)
#define DPPF(v, ctrl) __int_as_float(DPPI(__float_as_int(v), (ctrl)))
#define DPPF0(v, ctrl)                                                        \
  __int_as_float(__builtin_amdgcn_update_dpp(0, __float_as_int(v), (ctrl),    \
                                             0xF, 0xF, true))

// argmax combine stage: keep (max value, lowest index on ties)
#define AMAX_STAGE(CTRL)                                                      \
  {                                                                           \
    const float oz = DPPF(zz, CTRL);                                          \
    const int   oi = DPPI(ji, CTRL);                                          \
    if (oz > zz || (oz == zz && oi < ji)) { zz = oz; ji = oi; }               \
  }

// ---------------------------------------------------------------------------
// Phase 1: h0 = input_h @ W_reduce + b ; c0 = input_c @ W_reduce + b
// (~73% of HBM floor; unchanged)
// ---------------------------------------------------------------------------
__global__ __launch_bounds__(256, 3)
void reduce_kernel(const float* __restrict__ Xh, const float* __restrict__ Xc,
                   const float* __restrict__ W, const float* __restrict__ bv,
                   float* __restrict__ H0, float* __restrict__ C0) {
  __shared__ float xs[64 * 132];   // 64 rows x 128 k (pitch 132 to break banks)
  __shared__ float wsm[128 * 20];  // W chunk

  const int bid = blockIdx.x;
  const float* __restrict__ X = (bid < kB) ? Xh : Xc;
  float* __restrict__ O       = (bid < kB) ? H0 : C0;
  const int b = bid & (kB - 1);
  X += (size_t)b * kL * kHid;
  O += (size_t)b * kRowElems;

  const int tid  = threadIdx.x;
  const int wave = tid >> 6;
  const int lane = tid & 63;

  float acc[20];
#pragma unroll
  for (int d = 0; d < 20; ++d) acc[d] = 0.0f;

  for (int ch = 0; ch < 4; ++ch) {
    __syncthreads();
#pragma unroll
    for (int r = 0; r < 8; ++r) {
      int f   = r * 256 + tid;          // float4 index within chunk
      int row = f >> 5;
      int c4  = (f & 31) << 2;
      float4 v = *(const float4*)(X + row * kHid + ch * 128 + c4);
      *(float4*)(xs + row * 132 + c4) = v;
    }
#pragma unroll
    for (int r = 0; r < 10; ++r) {
      int f = r * 256 + tid;
      wsm[f] = W[ch * 2560 + f];
    }
    __syncthreads();
#pragma unroll
    for (int kk = 0; kk < 32; ++kk) {
      int k = wave * 32 + kk;
      float x = xs[lane * 132 + k];
      const float4* wp = (const float4*)(wsm + k * 20);
      float4 w0 = wp[0], w1 = wp[1], w2 = wp[2], w3 = wp[3], w4 = wp[4];
      acc[0]  = fmaf(x, w0.x, acc[0]);  acc[1]  = fmaf(x, w0.y, acc[1]);
      acc[2]  = fmaf(x, w0.z, acc[2]);  acc[3]  = fmaf(x, w0.w, acc[3]);
      acc[4]  = fmaf(x, w1.x, acc[4]);  acc[5]  = fmaf(x, w1.y, acc[5]);
      acc[6]  = fmaf(x, w1.z, acc[6]);  acc[7]  = fmaf(x, w1.w, acc[7]);
      acc[8]  = fmaf(x, w2.x, acc[8]);  acc[9]  = fmaf(x, w2.y, acc[9]);
      acc[10] = fmaf(x, w2.z, acc[10]); acc[11] = fmaf(x, w2.w, acc[11]);
      acc[12] = fmaf(x, w3.x, acc[12]); acc[13] = fmaf(x, w3.y, acc[13]);
      acc[14] = fmaf(x, w3.z, acc[14]); acc[15] = fmaf(x, w3.w, acc[15]);
      acc[16] = fmaf(x, w4.x, acc[16]); acc[17] = fmaf(x, w4.y, acc[17]);
      acc[18] = fmaf(x, w4.z, acc[18]); acc[19] = fmaf(x, w4.w, acc[19]);
    }
  }

  __syncthreads();
  float* red = xs;  // reuse as scratch: 4*64*20 = 5120 floats
#pragma unroll
  for (int d = 0; d < 20; ++d) red[wave * 1280 + lane * 20 + d] = acc[d];
  __syncthreads();
#pragma unroll
  for (int r = 0; r < 5; ++r) {
    int f = r * 256 + tid;  // 1280 outputs, f = t*20 + d
    float s = (red[f] + red[1280 + f]) + (red[2560 + f] + red[3840 + f]);
    O[f] = s + bv[f % 20];
  }
}

// LDS-weight TreeLSTM eval of one (pair, dim) unit — init pass only.
#define EVAL_UNIT(A_, B2_, PS_, DD_, HN_)                                     \
  {                                                                           \
    float ai = bcs[DD_], af = bcs[20 + DD_], ag = bcs[40 + DD_],              \
          au = bcs[60 + DD_], ao = bcs[80 + DD_];                             \
    const int xa_ = (A_)*20, xb_ = (B2_)*20, wr_ = (DD_)*44;                  \
    _Pragma("unroll")                                                         \
    for (int kq = 0; kq < 10; ++kq) {                                         \
      const float4 xq = (kq < 5)                                              \
          ? *(const float4*)(h_state + xa_ + kq * 4)                          \
          : *(const float4*)(h_state + xb_ + (kq - 5) * 4);                   \
      const float4 wi = *(const float4*)(Wt + wr_ + kq * 4);                  \
      const float4 wf = *(const float4*)(Wt + 880  + wr_ + kq * 4);           \
      const float4 wg = *(const float4*)(Wt + 1760 + wr_ + kq * 4);           \
      const float4 wu = *(const float4*)(Wt + 2640 + wr_ + kq * 4);           \
      const float4 wo = *(const float4*)(Wt + 3520 + wr_ + kq * 4);           \
      ai = fmaf(xq.x, wi.x, ai); ai = fmaf(xq.y, wi.y, ai);                   \
      ai = fmaf(xq.z, wi.z, ai); ai = fmaf(xq.w, wi.w, ai);                   \
      af = fmaf(xq.x, wf.x, af); af = fmaf(xq.y, wf.y, af);                   \
      af = fmaf(xq.z, wf.z, af); af = fmaf(xq.w, wf.w, af);                   \
      ag = fmaf(xq.x, wg.x, ag); ag = fmaf(xq.y, wg.y, ag);                   \
      ag = fmaf(xq.z, wg.z, ag); ag = fmaf(xq.w, wg.w, ag);                   \
      au = fmaf(xq.x, wu.x, au); au = fmaf(xq.y, wu.y, au);                   \
      au = fmaf(xq.z, wu.z, au); au = fmaf(xq.w, wu.w, au);                   \
      ao = fmaf(xq.x, wo.x, ao); ao = fmaf(xq.y, wo.y, ao);                   \
      ao = fmaf(xq.z, wo.z, ao); ao = fmaf(xq.w, wo.w, ao);                   \
    }                                                                         \
    const float cl_ = c_state[(A_)*20 + (DD_)],                               \
                cr_ = c_state[(B2_)*20 + (DD_)];                              \
    const float cn_ = cl_ * fsig(af + 1.0f) + cr_ * fsig(ag + 1.0f) +         \
                      ftanhf(au) * fsig(ai);                                  \
    (HN_) = fsig(ao) * ftanhf(cn_);                                           \
    nh[(PS_)*20 + (DD_)] = (HN_);                                             \
    nc[(PS_)*20 + (DD_)] = cn_;                                               \
  }

// Register-weight eval (main loop). Source rows come in as LDS pointers so
// the merged node can be read directly from nh/nc (no h_state round-trip).
#define EVAL_REGW(PHA_, PHB_, PCA_, PCB_, PS_)                                \
  {                                                                           \
    float xr[40];                                                             \
    _Pragma("unroll")                                                         \
    for (int q = 0; q < 5; ++q) {                                             \
      const float4 t = *(const float4*)((PHA_) + q * 4);                      \
      xr[q*4+0]=t.x; xr[q*4+1]=t.y; xr[q*4+2]=t.z; xr[q*4+3]=t.w;             \
    }                                                                         \
    _Pragma("unroll")                                                         \
    for (int q = 0; q < 5; ++q) {                                             \
      const float4 t = *(const float4*)((PHB_) + q * 4);                      \
      xr[20+q*4+0]=t.x; xr[20+q*4+1]=t.y; xr[20+q*4+2]=t.z; xr[20+q*4+3]=t.w; \
    }                                                                         \
    float si = bi, sfl = bfl, sfr = bfr, su = bu, so = bo;                    \
    _Pragma("unroll")                                                         \
    for (int kk = 0; kk < 40; ++kk) {                                         \
      si  = fmaf(xr[kk], w0[kk], si);                                         \
      sfl = fmaf(xr[kk], w1[kk], sfl);                                        \
      sfr = fmaf(xr[kk], w2[kk], sfr);                                        \
      su  = fmaf(xr[kk], w3[kk], su);                                         \
      so  = fmaf(xr[kk], w4[kk], so);                                         \
    }                                                                         \
    const float cl_ = (PCA_)[dd];                                             \
    const float cr_ = (PCB_)[dd];                                             \
    const float cn_ = cl_ * fsig(sfl + 1.0f) + cr_ * fsig(sfr + 1.0f) +       \
                      ftanhf(su) * fsig(si);                                  \
    const float hn_ = fsig(so) * ftanhf(cn_);                                 \
    nh[(PS_)*20 + dd] = hn_;                                                  \
    nc[(PS_)*20 + dd] = cn_;                                                  \
    part_ = hn_ * qq;                                                         \
  }

// ---------------------------------------------------------------------------
// Phase 2: per-row Gumbel tree pyramid, ONE WAVE per row.
// DPP reductions (no LDS-routed shuffles on the chain), register weights,
// 2-deep U prefetch, merge-bypass eval sources.
// ---------------------------------------------------------------------------
__global__ __launch_bounds__(64, 1)
void pyramid_kernel(const float* __restrict__ H0, const float* __restrict__ C0,
                    const float* __restrict__ Wc, const float* __restrict__ bcg,
                    const float* __restrict__ query, const float* __restrict__ U,
                    const int* __restrict__ length, float* __restrict__ out) {
  __shared__ float h_state[64 * 20];
  __shared__ float c_state[64 * 20];
  __shared__ float nh[63 * 20];     // cached pair h_new, by pair SLOT
  __shared__ float nc[63 * 20];     // cached pair c_new
  __shared__ float Wt[100 * 44];    // transposed W_comp: Wt[c][k], pitch 44
  __shared__ float bcs[100];
  __shared__ float qvs[20];

  const int b    = blockIdx.x;
  const int lane = threadIdx.x;     // one wave: lane == tid
  const int dd   = lane & 31;       // output dim within eval group
  const int ddc  = dd < 20 ? dd : 19;
  int len = length[b];
  len = len < 1 ? 1 : (len > 64 ? 64 : len);

  // ---- stage ----
  {
    const float4* h4 = (const float4*)(H0 + (size_t)b * kRowElems);
    const float4* c4 = (const float4*)(C0 + (size_t)b * kRowElems);
#pragma unroll
    for (int r = 0; r < 5; ++r) {
      int f = r * 64 + lane;  // 320 float4 per array
      ((float4*)h_state)[f] = h4[f];
      ((float4*)c_state)[f] = c4[f];
    }
  }
  for (int f = lane; f < 4000; f += 64) {
    int c = f / 40, k = f - c * 40;
    Wt[c * 44 + k] = Wc[k * 100 + c];
  }
  for (int f = lane; f < 100; f += 64) bcs[f] = bcg[f];
  if (lane < 20) qvs[lane] = query[lane];

  // per-lane register copies of position-indexed bookkeeping
  int   idx_r  = lane;   // position lane -> h/c slot
  int   pidx_r = lane;   // position lane -> nh/nc slot
  float lgt_r  = -FLT_MAX;

  const int col = lane < 62 ? lane : 62;  // U row has 63 entries
  const float u_row0 = U[b * kLM1 + col];
  float u_c = (kLM1 > 1) ? U[1 * (kB * kLM1) + b * kLM1 + col] : 0.0f;

  // ---- init: evaluate all 63 adjacent pairs (LDS weights, parallel) ----
#pragma unroll 1
  for (int r = 0; r < 20; ++r) {
    int uu = r * 64 + lane;
    if (uu < 1260) {
      int p = uu / 20, d2 = uu - p * 20;
      float hn_;
      EVAL_UNIT(p, p + 1, p, d2, hn_);
      (void)hn_;
    }
  }
  if (lane < 63) {
    float s = 0.0f;
#pragma unroll
    for (int q = 0; q < 5; ++q) {
      const float4 t  = *(const float4*)(nh  + lane * 20 + q * 4);
      const float4 qv = *(const float4*)(qvs + q * 4);
      s = fmaf(t.x, qv.x, s); s = fmaf(t.y, qv.y, s);
      s = fmaf(t.z, qv.z, s); s = fmaf(t.w, qv.w, s);
    }
    lgt_r = s;
  }

  // ---- load this lane's full gate-weight columns into registers (200) ----
  float w0[40], w1[40], w2[40], w3[40], w4[40];
#pragma unroll
  for (int q = 0; q < 10; ++q) {
    float4 t;
    t = *(const float4*)(Wt + (0  + ddc) * 44 + q * 4);
    w0[q*4+0]=t.x; w0[q*4+1]=t.y; w0[q*4+2]=t.z; w0[q*4+3]=t.w;
    t = *(const float4*)(Wt + (20 + ddc) * 44 + q * 4);
    w1[q*4+0]=t.x; w1[q*4+1]=t.y; w1[q*4+2]=t.z; w1[q*4+3]=t.w;
    t = *(const float4*)(Wt + (40 + ddc) * 44 + q * 4);
    w2[q*4+0]=t.x; w2[q*4+1]=t.y; w2[q*4+2]=t.z; w2[q*4+3]=t.w;
    t = *(const float4*)(Wt + (60 + ddc) * 44 + q * 4);
    w3[q*4+0]=t.x; w3[q*4+1]=t.y; w3[q*4+2]=t.z; w3[q*4+3]=t.w;
    t = *(const float4*)(Wt + (80 + ddc) * 44 + q * 4);
    w4[q*4+0]=t.x; w4[q*4+1]=t.y; w4[q*4+2]=t.z; w4[q*4+3]=t.w;
  }
  // Opaque pin: remat-from-LDS illegal after this (values live in VGPR/AGPR).
#pragma unroll
  for (int j = 0; j < 40; ++j) {
    asm volatile("" : "+v"(w0[j]), "+v"(w1[j]), "+v"(w2[j]),
                      "+v"(w3[j]), "+v"(w4[j]));
  }
  const float bi  = bcs[ddc],      bfl = bcs[20 + ddc], bfr = bcs[40 + ddc],
              bu  = bcs[60 + ddc], bo  = bcs[80 + ddc];
  const float qq  = qvs[ddc];

  float gcur = -__logf(-__logf(u_row0 + 1e-20f) + 1e-20f);

  const int nIter = len - 1;
#pragma unroll 1
  for (int i = 0; i < nIter; ++i) {
    const int n = kL - i;  // current sequence length

    // ---- z = logit + gumbel; argmax via DPP (ties -> lowest index) ----
    float zz = -FLT_MAX;
    int   ji = lane;
    if ((lane <= n - 2) && ((i + 1 + lane) < len)) zz = lgt_r + gcur;
    AMAX_STAGE(0xB1);   // xor1
    AMAX_STAGE(0x4E);   // xor2
    AMAX_STAGE(0x141);  // row_half_mirror
    AMAX_STAGE(0x140);  // row_mirror      -> every lane: its 16-row argmax
    AMAX_STAGE(0x142);  // row_bcast15     -> lanes 16-31 / 48-63 combine
    AMAX_STAGE(0x143);  // row_bcast31     -> lanes 48-63 hold global
    const int k = rdl_i(ji, 63);  // wave-uniform

    // ---- issue U load for row i+2 (2-deep pipeline, HBM latency covered) ----
    float u_d = 0.0f;
    if (i + 2 <= kLM1 - 1) u_d = U[(i + 2) * (kB * kLM1) + b * kLM1 + col];

    // ---- pre-shift lookups via readlane (VALU, no LDS) ----
    const int km1 = (k >= 1) ? k - 1 : 0;
    const int kp2 = (k <= n - 3) ? k + 2 : 0;
    const int tgt = rdl_i(idx_r,  k);
    const int psk = rdl_i(pidx_r, k);
    const int iA  = rdl_i(idx_r,  km1);
    const int pA  = rdl_i(pidx_r, km1);
    const int iB  = rdl_i(idx_r,  kp2);

    // ---- merge: winner's cached (h,c) -> state slot tgt (off-chain now) ----
    if (lane < 20) {
      h_state[tgt * 20 + lane] = nh[psk * 20 + lane];
      c_state[tgt * 20 + lane] = nc[psk * 20 + lane];
    }

    // ---- shift position-indexed registers via DPP row_shl:1 ----
    {
      int   sI = DPPI(idx_r,  0x101);
      int   sP = DPPI(pidx_r, 0x101);
      float sL = DPPF(lgt_r,  0x101);
      // cross-row boundaries: lane 15<-16, 31<-32, 47<-48
      const int   bi16 = rdl_i(idx_r, 16),  bi32 = rdl_i(idx_r, 32),
                  bi48 = rdl_i(idx_r, 48);
      const int   bp16 = rdl_i(pidx_r, 16), bp32 = rdl_i(pidx_r, 32),
                  bp48 = rdl_i(pidx_r, 48);
      const float bl16 = rdl_f(lgt_r, 16),  bl32 = rdl_f(lgt_r, 32),
                  bl48 = rdl_f(lgt_r, 48);
      if (lane == 15) { sI = bi16; sP = bp16; sL = bl16; }
      if (lane == 31) { sI = bi32; sP = bp32; sL = bl32; }
      if (lane == 47) { sI = bi48; sP = bp48; sL = bl48; }
      const bool doI = (lane >= k + 1) && (lane <= n - 2);
      const bool doP = (lane >= k + 1) && (lane <= n - 3);
      if (doI) idx_r = sI;
      if (doP) { pidx_r = sP; lgt_r = sL; }
    }

    // ---- evaluate the (<=2) invalidated pairs; merged node read from nh/nc
    if (i < len - 2) {
      const int  p    = lane >> 5;
      const bool hasB = (k >= 1) && (k <= n - 3);
      const float *pHA, *pHB, *pCA, *pCB;
      int PS2;
      if (p == 0 && k >= 1) {
        pHA = h_state + iA * 20;  pCA = c_state + iA * 20;
        pHB = nh + psk * 20;      pCB = nc + psk * 20;
        PS2 = pA;
      } else {  // group1, or group0 with k==0: A = merged node
        pHA = nh + psk * 20;      pCA = nc + psk * 20;
        pHB = h_state + iB * 20;  pCB = c_state + iB * 20;
        PS2 = psk;
      }
      const bool act = (dd < 20) && ((p == 0) || hasB);
      float part_ = 0.0f;
      if (act) { EVAL_REGW(pHA, pHB, pCA, pCB, PS2); }
      // per-32-group sum via DPP; totals land in lanes 31 (g0) and 63 (g1)
      part_ += DPPF0(part_, 0xB1);
      part_ += DPPF0(part_, 0x4E);
      part_ += DPPF0(part_, 0x141);
      part_ += DPPF0(part_, 0x140);
      part_ += DPPF0(part_, 0x142);
      const float vA = rdl_f(part_, 31);
      const float vB = rdl_f(part_, 63);
      const int   pos0 = (k >= 1) ? k - 1 : k;
      if (lane == pos0) lgt_r = vA;
      if (hasB && lane == k) lgt_r = vB;
    }

    // ---- gumbel transform for row i+1 (u_c loaded >=1 iteration ago) ----
    gcur = -__logf(-__logf(u_c + 1e-20f) + 1e-20f);
    u_c  = u_d;
  }

  const int root = rdl_i(idx_r, 0);
  if (lane < 20) {
    out[b * 20 + lane] = h_state[root * 20 + lane];
  }
}

}  // namespace

extern "C" void kernel_launch(void* const* d_in, const int* in_sizes, int n_in,
                              void* d_out, int out_size, void* d_ws, size_t ws_size,
                              hipStream_t stream) {
  const float* input_h  = (const float*)d_in[0];
  const float* input_c  = (const float*)d_in[1];
  const float* W_reduce = (const float*)d_in[2];
  const float* b_reduce = (const float*)d_in[3];
  const float* W_comp   = (const float*)d_in[4];
  const float* b_comp   = (const float*)d_in[5];
  const float* query    = (const float*)d_in[6];
  const float* u_noise  = (const float*)d_in[7];
  const int*   length   = (const int*)d_in[8];
  float* out = (float*)d_out;

  float* H0 = (float*)d_ws;
  float* C0 = H0 + (size_t)kB * kL * kLow;

  reduce_kernel<<<dim3(2 * kB), dim3(256), 0, stream>>>(
      input_h, input_c, W_reduce, b_reduce, H0, C0);
  pyramid_kernel<<<dim3(kB), dim3(64), 0, stream>>>(
      H0, C0, W_comp, b_comp, query, u_noise, length, out);
}